// Round 1
// 328.936 us; speedup vs baseline: 1.0120x; 1.0120x over previous
//
#include <hip/hip_runtime.h>

#define EPS 1e-10f
#define BLOCK 256
#define GRID1 2048
#define BGROUPS 1024  // float4 groups per block per sweep (= 4 * BLOCK)

// R5. R4 post-mortem: VGPR_Count=32 proves the compiler re-serialized the
// "16 in-flight loads" (payload alone needs 64 VGPRs). Also 5000 tiles over
// 2048 blocks = 2.44 tiles/block -> ~20% tail imbalance (occupancy 65%).
// Fixes: (a) inline-asm global_load_dwordx4 x8 + single s_waitcnt vmcnt(0)
// + sched_barrier(0) (rule #18) forces 8 loads in flight per wave;
// (b) uniform global sweeps (4 full + 1 predicated) -> every thread does
// exactly 5 identical batched iterations, zero imbalance.

typedef float f32x4 __attribute__((ext_vector_type(4)));
typedef int   i32x4 __attribute__((ext_vector_type(4)));

#define GLOAD(dst, ptr) \
  asm volatile("global_load_dwordx4 %0, %1, off" : "=v"(dst) : "v"(ptr))

__global__ __launch_bounds__(BLOCK) void sparse_loss_stage1(
    const float* __restrict__ pred,
    const int* __restrict__ y,
    const int* __restrict__ lamda_p,
    float* __restrict__ partials,   // [GRID1]
    long long nvec,                 // number of float4 groups
    long long total) {              // total element count
  const float lam = (float)(*lamda_p);
  float acc = 0.0f;  // accumulates +coef*log(arg); sign applied in stage 2

  const f32x4* __restrict__ pv = reinterpret_cast<const f32x4*>(pred);
  const i32x4* __restrict__ yv = reinterpret_cast<const i32x4*>(y);

#define ELEM(P, Y)                                   \
  {                                                  \
    const bool z = ((Y) == 0);                       \
    const float a = EPS + (z ? (1.0f - (P)) : (P));  \
    const float c = z ? 1.0f : lam;                  \
    acc = fmaf(c, __logf(a), acc);                   \
  }
#define ELEM4(A, B) ELEM(A[0], B[0]) ELEM(A[1], B[1]) ELEM(A[2], B[2]) ELEM(A[3], B[3])

#define ELEMM(P, Y, M)                               \
  {                                                  \
    const bool z = ((Y) == 0);                       \
    const float a = EPS + (z ? (1.0f - (P)) : (P));  \
    const float c = (z ? 1.0f : lam) * (M);          \
    acc = fmaf(c, __logf(a), acc);                   \
  }
#define ELEM4M(A, B, M) \
  ELEMM(A[0], B[0], M) ELEMM(A[1], B[1], M) ELEMM(A[2], B[2], M) ELEMM(A[3], B[3], M)

  const long long SWEEP = (long long)GRID1 * BGROUPS;  // groups per full sweep
  const long long nfull = nvec / SWEEP;
  const long long j0 = (long long)blockIdx.x * BGROUPS + threadIdx.x;

  // ---- full sweeps: 8 forced-in-flight dwordx4 loads, one wait, compute ----
  for (long long s = 0; s < nfull; ++s) {
    const long long b = s * SWEEP + j0;
    const f32x4* pp = pv + b;
    const i32x4* yp = yv + b;
    f32x4 a0, a1, a2, a3;
    i32x4 q0, q1, q2, q3;
    GLOAD(a0, pp);
    GLOAD(a1, pp + 256);
    GLOAD(a2, pp + 512);
    GLOAD(a3, pp + 768);
    GLOAD(q0, yp);
    GLOAD(q1, yp + 256);
    GLOAD(q2, yp + 512);
    GLOAD(q3, yp + 768);
    asm volatile("s_waitcnt vmcnt(0)" ::: "memory");
    __builtin_amdgcn_sched_barrier(0);
    ELEM4(a0, q0)
    ELEM4(a1, q1)
    ELEM4(a2, q2)
    ELEM4(a3, q3)
  }

  // ---- predicated remainder sweep (index-clamped, coef-masked) ----
  const long long rb = nfull * SWEEP;
  if (rb + (long long)blockIdx.x * BGROUPS < nvec) {
    const long long b = rb + j0;
    const long long jA = b, jB = b + 256, jC = b + 512, jD = b + 768;
    const float mA = (jA < nvec) ? 1.0f : 0.0f;
    const float mB = (jB < nvec) ? 1.0f : 0.0f;
    const float mC = (jC < nvec) ? 1.0f : 0.0f;
    const float mD = (jD < nvec) ? 1.0f : 0.0f;
    const long long cA = (jA < nvec) ? jA : 0;
    const long long cB = (jB < nvec) ? jB : 0;
    const long long cC = (jC < nvec) ? jC : 0;
    const long long cD = (jD < nvec) ? jD : 0;
    f32x4 a0, a1, a2, a3;
    i32x4 q0, q1, q2, q3;
    GLOAD(a0, pv + cA);
    GLOAD(a1, pv + cB);
    GLOAD(a2, pv + cC);
    GLOAD(a3, pv + cD);
    GLOAD(q0, yv + cA);
    GLOAD(q1, yv + cB);
    GLOAD(q2, yv + cC);
    GLOAD(q3, yv + cD);
    asm volatile("s_waitcnt vmcnt(0)" ::: "memory");
    __builtin_amdgcn_sched_barrier(0);
    ELEM4M(a0, q0, mA)
    ELEM4M(a1, q1, mB)
    ELEM4M(a2, q2, mC)
    ELEM4M(a3, q3, mD)
  }

  // ---- scalar tail (total % 4 != 0 -- not the case here, but cheap) ----
  const long long gtid = (long long)blockIdx.x * BLOCK + threadIdx.x;
  const long long gstride = (long long)gridDim.x * BLOCK;
  for (long long j = nvec * 4 + gtid; j < total; j += gstride) {
    const float p = pred[j];
    ELEM(p, y[j])
  }
#undef ELEM
#undef ELEM4
#undef ELEMM
#undef ELEM4M

  // wave64 butterfly reduce
  for (int off = 32; off > 0; off >>= 1)
    acc += __shfl_down(acc, off, 64);

  __shared__ float ssum[4];
  const int lane = threadIdx.x & 63;
  const int wave = threadIdx.x >> 6;
  if (lane == 0) ssum[wave] = acc;
  __syncthreads();

  if (threadIdx.x == 0)
    partials[blockIdx.x] = ssum[0] + ssum[1] + ssum[2] + ssum[3];
}

__global__ __launch_bounds__(BLOCK) void sparse_loss_stage2(
    const float* __restrict__ partials,  // [GRID1]
    float* __restrict__ out,
    float inv_total) {
  float acc = 0.0f;
  for (int i = threadIdx.x; i < GRID1; i += BLOCK)
    acc += partials[i];

  for (int off = 32; off > 0; off >>= 1)
    acc += __shfl_down(acc, off, 64);

  __shared__ float ssum[4];
  const int lane = threadIdx.x & 63;
  const int wave = threadIdx.x >> 6;
  if (lane == 0) ssum[wave] = acc;
  __syncthreads();

  if (threadIdx.x == 0)
    out[0] = -(ssum[0] + ssum[1] + ssum[2] + ssum[3]) * inv_total;
}

extern "C" void kernel_launch(void* const* d_in, const int* in_sizes, int n_in,
                              void* d_out, int out_size, void* d_ws, size_t ws_size,
                              hipStream_t stream) {
  const float* pred = (const float*)d_in[0];
  const int* y = (const int*)d_in[1];
  const int* lamda = (const int*)d_in[2];
  float* out = (float*)d_out;
  float* partials = (float*)d_ws;  // 2048 floats = 8 KB scratch

  const long long total = (long long)in_sizes[0];
  const long long nvec = total / 4;
  const float inv_total = 1.0f / (float)total;

  sparse_loss_stage1<<<GRID1, BLOCK, 0, stream>>>(pred, y, lamda, partials,
                                                  nvec, total);
  sparse_loss_stage2<<<1, BLOCK, 0, stream>>>(partials, out, inv_total);
}

// Round 3
// 320.140 us; speedup vs baseline: 1.0398x; 1.0275x over previous
//
#include <hip/hip_runtime.h>

#define EPS 1e-10f
#define BLOCK 256
#define GRID1 2048
#define BGROUPS 1024  // float4 groups per block per sweep (= 4 * BLOCK)

// R7. R6 (asm-tuple vmcnt pipeline) crashed the toolchain -> reverted to the
// proven R5 shape with plain compiler-scheduled loads (R4 proved identical
// perf to forced-asm MLP). R3/R4/R5 post-mortem: 2.8 TB/s delivered
// (1.4 HBM + 1.4 L3, FETCH == pred size) across three issue structures ->
// CU-side limiters ruled out (4.6 B/cy/CU << L1 path; occupancy maxed).
// Model: full-duplex fabric, read-only inbound ceiling ~3.15 TB/s (m13's
// 6.29 copy = 3.15 in + 3.15 out). We are at 89% of it.
// R7 tests the last cheap lever: (a) non-temporal loads for pred (stop
// churning 164MB/iter through L2/LLC; keep y fully LLC-resident),
// (b) bijective XCD-chunked block swizzle for per-XCD stream contiguity.
// Null (+-3%) => inbound ceiling confirmed => ROOFLINE.

typedef float f32x4 __attribute__((ext_vector_type(4)));
typedef int   i32x4 __attribute__((ext_vector_type(4)));

__global__ __launch_bounds__(BLOCK) void sparse_loss_stage1(
    const float* __restrict__ pred,
    const int* __restrict__ y,
    const int* __restrict__ lamda_p,
    float* __restrict__ partials,   // [GRID1]
    long long nvec,                 // number of float4 groups
    long long total) {              // total element count
  const float lam = (float)(*lamda_p);
  float acc = 0.0f;  // accumulates +coef*log(arg); sign applied in stage 2

  const f32x4* __restrict__ pv = reinterpret_cast<const f32x4*>(pred);
  const i32x4* __restrict__ yv = reinterpret_cast<const i32x4*>(y);

  // Bijective XCD-chunked swizzle (2048 % 8 == 0): XCD k owns blocks
  // [k*256, (k+1)*256) of the swizzled id space -> contiguous address chunk.
  const int bid = (int)((blockIdx.x & 7) * (GRID1 / 8) + (blockIdx.x >> 3));

#define ELEM(P, Y)                                   \
  {                                                  \
    const bool z = ((Y) == 0);                       \
    const float a = EPS + (z ? (1.0f - (P)) : (P));  \
    const float c = z ? 1.0f : lam;                  \
    acc = fmaf(c, __logf(a), acc);                   \
  }
#define ELEM4(A, B) ELEM(A[0], B[0]) ELEM(A[1], B[1]) ELEM(A[2], B[2]) ELEM(A[3], B[3])

#define ELEMM(P, Y, M)                               \
  {                                                  \
    const bool z = ((Y) == 0);                       \
    const float a = EPS + (z ? (1.0f - (P)) : (P));  \
    const float c = (z ? 1.0f : lam) * (M);          \
    acc = fmaf(c, __logf(a), acc);                   \
  }
#define ELEM4M(A, B, M) \
  ELEMM(A[0], B[0], M) ELEMM(A[1], B[1], M) ELEMM(A[2], B[2], M) ELEMM(A[3], B[3], M)

  const long long SWEEP = (long long)GRID1 * BGROUPS;  // groups per full sweep
  const long long nfull = nvec / SWEEP;
  const long long j0 = (long long)bid * BGROUPS + threadIdx.x;

  // ---- full sweeps: 8 independent dwordx4 loads, compiler-scheduled ----
  for (long long s = 0; s < nfull; ++s) {
    const long long b = s * SWEEP + j0;
    const f32x4* pp = pv + b;
    const i32x4* yp = yv + b;
    f32x4 a0, a1, a2, a3;
    i32x4 q0, q1, q2, q3;
    a0 = __builtin_nontemporal_load(pp);
    a1 = __builtin_nontemporal_load(pp + 256);
    a2 = __builtin_nontemporal_load(pp + 512);
    a3 = __builtin_nontemporal_load(pp + 768);
    q0 = yp[0];
    q1 = yp[256];
    q2 = yp[512];
    q3 = yp[768];
    ELEM4(a0, q0)
    ELEM4(a1, q1)
    ELEM4(a2, q2)
    ELEM4(a3, q3)
  }

  // ---- predicated remainder sweep (index-clamped, coef-masked) ----
  const long long rb = nfull * SWEEP;
  if (rb + (long long)bid * BGROUPS < nvec) {
    const long long b = rb + j0;
    const long long jA = b, jB = b + 256, jC = b + 512, jD = b + 768;
    const float mA = (jA < nvec) ? 1.0f : 0.0f;
    const float mB = (jB < nvec) ? 1.0f : 0.0f;
    const float mC = (jC < nvec) ? 1.0f : 0.0f;
    const float mD = (jD < nvec) ? 1.0f : 0.0f;
    const long long cA = (jA < nvec) ? jA : 0;
    const long long cB = (jB < nvec) ? jB : 0;
    const long long cC = (jC < nvec) ? jC : 0;
    const long long cD = (jD < nvec) ? jD : 0;
    f32x4 a0, a1, a2, a3;
    i32x4 q0, q1, q2, q3;
    a0 = __builtin_nontemporal_load(pv + cA);
    a1 = __builtin_nontemporal_load(pv + cB);
    a2 = __builtin_nontemporal_load(pv + cC);
    a3 = __builtin_nontemporal_load(pv + cD);
    q0 = yv[cA];
    q1 = yv[cB];
    q2 = yv[cC];
    q3 = yv[cD];
    ELEM4M(a0, q0, mA)
    ELEM4M(a1, q1, mB)
    ELEM4M(a2, q2, mC)
    ELEM4M(a3, q3, mD)
  }

  // ---- scalar tail (total % 4 != 0 -- not the case here, but cheap) ----
  const long long gtid = (long long)bid * BLOCK + threadIdx.x;
  const long long gstride = (long long)gridDim.x * BLOCK;
  for (long long j = nvec * 4 + gtid; j < total; j += gstride) {
    const float p = pred[j];
    ELEM(p, y[j])
  }
#undef ELEM
#undef ELEM4
#undef ELEMM
#undef ELEM4M

  // wave64 butterfly reduce
  for (int off = 32; off > 0; off >>= 1)
    acc += __shfl_down(acc, off, 64);

  __shared__ float ssum[4];
  const int lane = threadIdx.x & 63;
  const int wave = threadIdx.x >> 6;
  if (lane == 0) ssum[wave] = acc;
  __syncthreads();

  if (threadIdx.x == 0)
    partials[bid] = ssum[0] + ssum[1] + ssum[2] + ssum[3];
}

__global__ __launch_bounds__(BLOCK) void sparse_loss_stage2(
    const float* __restrict__ partials,  // [GRID1]
    float* __restrict__ out,
    float inv_total) {
  float acc = 0.0f;
  for (int i = threadIdx.x; i < GRID1; i += BLOCK)
    acc += partials[i];

  for (int off = 32; off > 0; off >>= 1)
    acc += __shfl_down(acc, off, 64);

  __shared__ float ssum[4];
  const int lane = threadIdx.x & 63;
  const int wave = threadIdx.x >> 6;
  if (lane == 0) ssum[wave] = acc;
  __syncthreads();

  if (threadIdx.x == 0)
    out[0] = -(ssum[0] + ssum[1] + ssum[2] + ssum[3]) * inv_total;
}

extern "C" void kernel_launch(void* const* d_in, const int* in_sizes, int n_in,
                              void* d_out, int out_size, void* d_ws, size_t ws_size,
                              hipStream_t stream) {
  const float* pred = (const float*)d_in[0];
  const int* y = (const int*)d_in[1];
  const int* lamda = (const int*)d_in[2];
  float* out = (float*)d_out;
  float* partials = (float*)d_ws;  // 2048 floats = 8 KB scratch

  const long long total = (long long)in_sizes[0];
  const long long nvec = total / 4;
  const float inv_total = 1.0f / (float)total;

  sparse_loss_stage1<<<GRID1, BLOCK, 0, stream>>>(pred, y, lamda, partials,
                                                  nvec, total);
  sparse_loss_stage2<<<1, BLOCK, 0, stream>>>(partials, out, inv_total);
}

// Round 4
// 302.309 us; speedup vs baseline: 1.1012x; 1.0590x over previous
//
#include <hip/hip_runtime.h>

#define EPS 1e-10f
#define BLOCK 256
#define GRID1 2048
#define BGROUPS 1024  // float4 groups per block per sweep (= 4 * BLOCK)

// R8. R7 post-mortem: nt-pred + XCD swizzle -> 117->96.6us, 3.39 TB/s
// delivered inbound (1.7 HBM + 1.7 LLC). The 3.15 TB/s inbound-ceiling model
// is falsified; harness memset shows 6.8 TB/s (85% peak) is reachable.
// R8 single change: y loads also non-temporal -> both streams pure-HBM.
//   - If HBM read BW is memset-class: stage1 -> ~60-70us (327.68MB @ ~5TB/s).
//   - If a real ~3.4 TB/s inbound ceiling exists: unchanged (same total
//     inbound bytes, different source) -> declare ROOFLINE next round.

typedef float f32x4 __attribute__((ext_vector_type(4)));
typedef int   i32x4 __attribute__((ext_vector_type(4)));

__global__ __launch_bounds__(BLOCK) void sparse_loss_stage1(
    const float* __restrict__ pred,
    const int* __restrict__ y,
    const int* __restrict__ lamda_p,
    float* __restrict__ partials,   // [GRID1]
    long long nvec,                 // number of float4 groups
    long long total) {              // total element count
  const float lam = (float)(*lamda_p);
  float acc = 0.0f;  // accumulates +coef*log(arg); sign applied in stage 2

  const f32x4* __restrict__ pv = reinterpret_cast<const f32x4*>(pred);
  const i32x4* __restrict__ yv = reinterpret_cast<const i32x4*>(y);

  // Bijective XCD-chunked swizzle (2048 % 8 == 0): XCD k owns blocks
  // [k*256, (k+1)*256) of the swizzled id space -> contiguous address chunk.
  const int bid = (int)((blockIdx.x & 7) * (GRID1 / 8) + (blockIdx.x >> 3));

#define ELEM(P, Y)                                   \
  {                                                  \
    const bool z = ((Y) == 0);                       \
    const float a = EPS + (z ? (1.0f - (P)) : (P));  \
    const float c = z ? 1.0f : lam;                  \
    acc = fmaf(c, __logf(a), acc);                   \
  }
#define ELEM4(A, B) ELEM(A[0], B[0]) ELEM(A[1], B[1]) ELEM(A[2], B[2]) ELEM(A[3], B[3])

#define ELEMM(P, Y, M)                               \
  {                                                  \
    const bool z = ((Y) == 0);                       \
    const float a = EPS + (z ? (1.0f - (P)) : (P));  \
    const float c = (z ? 1.0f : lam) * (M);          \
    acc = fmaf(c, __logf(a), acc);                   \
  }
#define ELEM4M(A, B, M) \
  ELEMM(A[0], B[0], M) ELEMM(A[1], B[1], M) ELEMM(A[2], B[2], M) ELEMM(A[3], B[3], M)

  const long long SWEEP = (long long)GRID1 * BGROUPS;  // groups per full sweep
  const long long nfull = nvec / SWEEP;
  const long long j0 = (long long)bid * BGROUPS + threadIdx.x;

  // ---- full sweeps: 8 independent dwordx4 loads, compiler-scheduled ----
  for (long long s = 0; s < nfull; ++s) {
    const long long b = s * SWEEP + j0;
    const f32x4* pp = pv + b;
    const i32x4* yp = yv + b;
    f32x4 a0, a1, a2, a3;
    i32x4 q0, q1, q2, q3;
    a0 = __builtin_nontemporal_load(pp);
    a1 = __builtin_nontemporal_load(pp + 256);
    a2 = __builtin_nontemporal_load(pp + 512);
    a3 = __builtin_nontemporal_load(pp + 768);
    q0 = __builtin_nontemporal_load(yp);
    q1 = __builtin_nontemporal_load(yp + 256);
    q2 = __builtin_nontemporal_load(yp + 512);
    q3 = __builtin_nontemporal_load(yp + 768);
    ELEM4(a0, q0)
    ELEM4(a1, q1)
    ELEM4(a2, q2)
    ELEM4(a3, q3)
  }

  // ---- predicated remainder sweep (index-clamped, coef-masked) ----
  const long long rb = nfull * SWEEP;
  if (rb + (long long)bid * BGROUPS < nvec) {
    const long long b = rb + j0;
    const long long jA = b, jB = b + 256, jC = b + 512, jD = b + 768;
    const float mA = (jA < nvec) ? 1.0f : 0.0f;
    const float mB = (jB < nvec) ? 1.0f : 0.0f;
    const float mC = (jC < nvec) ? 1.0f : 0.0f;
    const float mD = (jD < nvec) ? 1.0f : 0.0f;
    const long long cA = (jA < nvec) ? jA : 0;
    const long long cB = (jB < nvec) ? jB : 0;
    const long long cC = (jC < nvec) ? jC : 0;
    const long long cD = (jD < nvec) ? jD : 0;
    f32x4 a0, a1, a2, a3;
    i32x4 q0, q1, q2, q3;
    a0 = __builtin_nontemporal_load(pv + cA);
    a1 = __builtin_nontemporal_load(pv + cB);
    a2 = __builtin_nontemporal_load(pv + cC);
    a3 = __builtin_nontemporal_load(pv + cD);
    q0 = __builtin_nontemporal_load(yv + cA);
    q1 = __builtin_nontemporal_load(yv + cB);
    q2 = __builtin_nontemporal_load(yv + cC);
    q3 = __builtin_nontemporal_load(yv + cD);
    ELEM4M(a0, q0, mA)
    ELEM4M(a1, q1, mB)
    ELEM4M(a2, q2, mC)
    ELEM4M(a3, q3, mD)
  }

  // ---- scalar tail (total % 4 != 0 -- not the case here, but cheap) ----
  const long long gtid = (long long)bid * BLOCK + threadIdx.x;
  const long long gstride = (long long)gridDim.x * BLOCK;
  for (long long j = nvec * 4 + gtid; j < total; j += gstride) {
    const float p = pred[j];
    ELEM(p, y[j])
  }
#undef ELEM
#undef ELEM4
#undef ELEMM
#undef ELEM4M

  // wave64 butterfly reduce
  for (int off = 32; off > 0; off >>= 1)
    acc += __shfl_down(acc, off, 64);

  __shared__ float ssum[4];
  const int lane = threadIdx.x & 63;
  const int wave = threadIdx.x >> 6;
  if (lane == 0) ssum[wave] = acc;
  __syncthreads();

  if (threadIdx.x == 0)
    partials[bid] = ssum[0] + ssum[1] + ssum[2] + ssum[3];
}

__global__ __launch_bounds__(BLOCK) void sparse_loss_stage2(
    const float* __restrict__ partials,  // [GRID1]
    float* __restrict__ out,
    float inv_total) {
  float acc = 0.0f;
  for (int i = threadIdx.x; i < GRID1; i += BLOCK)
    acc += partials[i];

  for (int off = 32; off > 0; off >>= 1)
    acc += __shfl_down(acc, off, 64);

  __shared__ float ssum[4];
  const int lane = threadIdx.x & 63;
  const int wave = threadIdx.x >> 6;
  if (lane == 0) ssum[wave] = acc;
  __syncthreads();

  if (threadIdx.x == 0)
    out[0] = -(ssum[0] + ssum[1] + ssum[2] + ssum[3]) * inv_total;
}

extern "C" void kernel_launch(void* const* d_in, const int* in_sizes, int n_in,
                              void* d_out, int out_size, void* d_ws, size_t ws_size,
                              hipStream_t stream) {
  const float* pred = (const float*)d_in[0];
  const int* y = (const int*)d_in[1];
  const int* lamda = (const int*)d_in[2];
  float* out = (float*)d_out;
  float* partials = (float*)d_ws;  // 2048 floats = 8 KB scratch

  const long long total = (long long)in_sizes[0];
  const long long nvec = total / 4;
  const float inv_total = 1.0f / (float)total;

  sparse_loss_stage1<<<GRID1, BLOCK, 0, stream>>>(pred, y, lamda, partials,
                                                  nvec, total);
  sparse_loss_stage2<<<1, BLOCK, 0, stream>>>(partials, out, inv_total);
}